// Round 9
// baseline (31.698 us; speedup 1.0000x reference)
//
#include <hip/hip_runtime.h>

// UpsampleFlow2: Gaussian Nadaraya-Watson upsampling.
// out [B,3,N] = (sum_s k*f)/(sum_s k), k = exp(-|x-y|^2/r^2).
// exp(-|x|^2/r^2) cancels in num/den ->
//   k' = exp2( fma(px,ax, fma(py,ay, fma(pz,az, bias))) )
//   a = c2*y, bias = cy*|y|^2, c2=2*log2e/r^2, cy=-log2e/r^2.
//
// R9: pk over QUERY pairs at 4 waves/SIMD. R5 measured 28.6 cyc/wave-pair
// (88% VALUBusy, 4 w/SIMD); 14 of those are scalar fma -> v_pk_fma_f32
// halves them, but only in the issue-bound regime (R6's 2 w/SIMD null).
// LDS stores PRE-SPLATTED sparse constants (ax,ax,ay,ay)... so v2f operands
// alias ds_read_b128 register pairs directly -- zero splat movs.
// PPT=4 (2 v2f query pairs), SC=32, CHUNK=64 -> 1024 blocks = 4 w/SIMD.

typedef float v2f __attribute__((ext_vector_type(2)));

constexpr int B_ = 4, N_ = 8192, S_ = 2048;
constexpr int BLOCK = 256, PPT = 4, NQ = PPT / 2;   // 2 query pairs
constexpr int PTS_PER_BLOCK = BLOCK * PPT;      // 1024
constexpr int NBPB = N_ / PTS_PER_BLOCK;        // 8
constexpr int NB = B_ * NBPB;                   // 32
constexpr int BN = B_ * N_;                     // 32768
constexpr float LOG2E = 1.4426950408889634f;

#define PK_FMA(d, a, b, c) \
    asm("v_pk_fma_f32 %0, %1, %2, %3" : "=v"(d) : "v"(a), "v"(b), "v"(c))
#define PK_FMA_ACC(acc, a, b) \
    asm("v_pk_fma_f32 %0, %1, %2, %0" : "+v"(acc) : "v"(a), "v"(b))
#define PK_ADD_ACC(acc, a) \
    asm("v_pk_add_f32 %0, %1, %0" : "+v"(acc) : "v"(a))

template <int CHUNK>
__global__ __launch_bounds__(BLOCK, 4) void uf2_main(
    const float* __restrict__ xyz,
    const float* __restrict__ sxyz,
    const float* __restrict__ sflow,
    const int* __restrict__ resol,
    float4* __restrict__ part)
{
    __shared__ float4 A1[CHUNK];   // (ax, ax, ay, ay)
    __shared__ float4 A2[CHUNK];   // (az, az, bias, bias)
    __shared__ float4 F1[CHUNK];   // (fx, fx, fy, fy)
    __shared__ v2f    F2[CHUNK];   // (fz, fz)

    const int nb = blockIdx.x % NB;
    const int sc = blockIdx.x / NB;
    const int b  = nb / NBPB;
    const int n0 = (nb % NBPB) * PTS_PER_BLOCK;
    const int s0 = sc * CHUNK;

    const float r = (float)resol[0];            // INITIAL_RADIUS(=1)*resol
    const float inv_r2 = 1.0f / (r * r);
    const float c2 = 2.0f * inv_r2 * LOG2E;
    const float cy = -inv_r2 * LOG2E;

    // ---- stage sparse chunk, pre-splatted for pk consumption ----
    const float* yb = sxyz  + b * 3 * S_;
    const float* fb = sflow + b * 3 * S_;
    for (int t = threadIdx.x; t < CHUNK; t += BLOCK) {
        const int s = s0 + t;
        const float yx = yb[s], yy = yb[S_ + s], yz = yb[2 * S_ + s];
        const float fx = fb[s], fy = fb[S_ + s], fz = fb[2 * S_ + s];
        const float ax = c2 * yx, ay = c2 * yy, az = c2 * yz;
        const float bias = cy * (yx * yx + yy * yy + yz * yz);
        A1[t] = make_float4(ax, ax, ay, ay);
        A2[t] = make_float4(az, az, bias, bias);
        F1[t] = make_float4(fx, fx, fy, fy);
        F2[t] = (v2f){fz, fz};
    }
    __syncthreads();

    // ---- per-thread query points as v2f pairs ----
    const float* xb = xyz + b * 3 * N_;
    v2f px2[NQ], py2[NQ], pz2[NQ];
    v2f acx[NQ], acy[NQ], acz[NQ], acw[NQ];
#pragma unroll
    for (int q = 0; q < NQ; ++q) {
        const int na = n0 + threadIdx.x + (2 * q) * BLOCK;
        const int nc = na + BLOCK;
        px2[q] = (v2f){xb[na], xb[nc]};
        py2[q] = (v2f){xb[N_ + na], xb[N_ + nc]};
        pz2[q] = (v2f){xb[2 * N_ + na], xb[2 * N_ + nc]};
        acx[q] = (v2f){0.f, 0.f}; acy[q] = (v2f){0.f, 0.f};
        acz[q] = (v2f){0.f, 0.f}; acw[q] = (v2f){0.f, 0.f};
    }

    // ---- main loop: 3 b128 + 1 b64 broadcast reads; pk math per t ----
#pragma unroll 2
    for (int t = 0; t < CHUNK; ++t) {
        const float4 a1 = A1[t];           // regs v[n..n+3]
        const float4 a2 = A2[t];
        const float4 f1 = F1[t];
        const v2f    fz2 = F2[t];
        // zero-cost pair views of the b128 results
        const v2f ax2 = (v2f){a1.x, a1.y}, ay2 = (v2f){a1.z, a1.w};
        const v2f az2 = (v2f){a2.x, a2.y}, bi2 = (v2f){a2.z, a2.w};
        const v2f fx2 = (v2f){f1.x, f1.y}, fy2 = (v2f){f1.z, f1.w};
#pragma unroll
        for (int q = 0; q < NQ; ++q) {
            v2f e2;
            PK_FMA(e2, pz2[q], az2, bi2);
            PK_FMA_ACC(e2, py2[q], ay2);
            PK_FMA_ACC(e2, px2[q], ax2);
            v2f k2;
            k2.x = __builtin_amdgcn_exp2f(e2.x);
            k2.y = __builtin_amdgcn_exp2f(e2.y);
            PK_FMA_ACC(acx[q], k2, fx2);
            PK_FMA_ACC(acy[q], k2, fy2);
            PK_FMA_ACC(acz[q], k2, fz2);
            PK_ADD_ACC(acw[q], k2);
        }
    }

    // ---- write partials (coalesced float4) ----
#pragma unroll
    for (int q = 0; q < NQ; ++q) {
        const int ga = b * N_ + n0 + threadIdx.x + (2 * q) * BLOCK;
        part[(size_t)sc * BN + ga] =
            make_float4(acx[q].x, acy[q].x, acz[q].x, acw[q].x);
        part[(size_t)sc * BN + ga + BLOCK] =
            make_float4(acx[q].y, acy[q].y, acz[q].y, acw[q].y);
    }
}

__global__ __launch_bounds__(BLOCK) void uf2_combine(
    const float4* __restrict__ part, float* __restrict__ out, int SC)
{
    const int g = blockIdx.x * BLOCK + threadIdx.x;   // 0..BN-1
    float4 s0 = make_float4(0.f, 0.f, 0.f, 0.f);
    float4 s1 = s0, s2 = s0, s3 = s0;
    int c = 0;
    for (; c + 4 <= SC; c += 4) {
        const float4 p0 = part[(size_t)(c + 0) * BN + g];
        const float4 p1 = part[(size_t)(c + 1) * BN + g];
        const float4 p2 = part[(size_t)(c + 2) * BN + g];
        const float4 p3 = part[(size_t)(c + 3) * BN + g];
        s0.x += p0.x; s0.y += p0.y; s0.z += p0.z; s0.w += p0.w;
        s1.x += p1.x; s1.y += p1.y; s1.z += p1.z; s1.w += p1.w;
        s2.x += p2.x; s2.y += p2.y; s2.z += p2.z; s2.w += p2.w;
        s3.x += p3.x; s3.y += p3.y; s3.z += p3.z; s3.w += p3.w;
    }
    for (; c < SC; ++c) {
        const float4 p = part[(size_t)c * BN + g];
        s0.x += p.x; s0.y += p.y; s0.z += p.z; s0.w += p.w;
    }
    const float sx = (s0.x + s1.x) + (s2.x + s3.x);
    const float sy = (s0.y + s1.y) + (s2.y + s3.y);
    const float sz = (s0.z + s1.z) + (s2.z + s3.z);
    const float sw = (s0.w + s1.w) + (s2.w + s3.w);
    const float inv = 1.0f / sw;
    const int b = g >> 13;            // /8192
    const int n = g & (N_ - 1);
    float* ob = out + b * 3 * N_;
    ob[n]          = sx * inv;
    ob[N_ + n]     = sy * inv;
    ob[2 * N_ + n] = sz * inv;
}

// Fallback (ws too small): single kernel, full S staged in LDS, direct out.
__global__ __launch_bounds__(BLOCK, 1) void uf2_fused(
    const float* __restrict__ xyz,
    const float* __restrict__ sxyz,
    const float* __restrict__ sflow,
    const int* __restrict__ resol,
    float* __restrict__ out)
{
    constexpr int FPPT = 4;
    constexpr int PTS = BLOCK * FPPT;
    __shared__ float4 As[S_];
    __shared__ float4 Fs[S_];

    const int nb = blockIdx.x;
    const int b  = nb / (N_ / PTS);
    const int n0 = (nb % (N_ / PTS)) * PTS;

    const float r = (float)resol[0];
    const float inv_r2 = 1.0f / (r * r);
    const float c2 = 2.0f * inv_r2 * LOG2E;
    const float cy = -inv_r2 * LOG2E;

    const float* yb = sxyz  + b * 3 * S_;
    const float* fb = sflow + b * 3 * S_;
    for (int t = threadIdx.x; t < S_; t += BLOCK) {
        const float yx = yb[t], yy = yb[S_ + t], yz = yb[2 * S_ + t];
        const float fx = fb[t], fy = fb[S_ + t], fz = fb[2 * S_ + t];
        As[t] = make_float4(c2 * yx, c2 * yy, c2 * yz,
                            cy * (yx * yx + yy * yy + yz * yz));
        Fs[t] = make_float4(fx, fy, fz, 0.0f);
    }
    __syncthreads();

    const float* xb = xyz + b * 3 * N_;
    float px[FPPT], py[FPPT], pz[FPPT];
    float4 acc[FPPT];
#pragma unroll
    for (int p = 0; p < FPPT; ++p) {
        const int n = n0 + threadIdx.x + p * BLOCK;
        px[p] = xb[n]; py[p] = xb[N_ + n]; pz[p] = xb[2 * N_ + n];
        acc[p] = make_float4(0.f, 0.f, 0.f, 0.f);
    }
#pragma unroll 4
    for (int t = 0; t < S_; ++t) {
        const float4 a = As[t];
        const float4 f = Fs[t];
#pragma unroll
        for (int p = 0; p < FPPT; ++p) {
            float e = fmaf(pz[p], a.z, a.w);
            e = fmaf(py[p], a.y, e);
            e = fmaf(px[p], a.x, e);
            const float k = __builtin_amdgcn_exp2f(e);
            acc[p].x = fmaf(k, f.x, acc[p].x);
            acc[p].y = fmaf(k, f.y, acc[p].y);
            acc[p].z = fmaf(k, f.z, acc[p].z);
            acc[p].w += k;
        }
    }
#pragma unroll
    for (int p = 0; p < FPPT; ++p) {
        const int n = n0 + threadIdx.x + p * BLOCK;
        const float inv = 1.0f / acc[p].w;
        float* ob = out + b * 3 * N_;
        ob[n]          = acc[p].x * inv;
        ob[N_ + n]     = acc[p].y * inv;
        ob[2 * N_ + n] = acc[p].z * inv;
    }
}

extern "C" void kernel_launch(void* const* d_in, const int* in_sizes, int n_in,
                              void* d_out, int out_size, void* d_ws, size_t ws_size,
                              hipStream_t stream)
{
    const float* xyz   = (const float*)d_in[0];
    const float* sxyz  = (const float*)d_in[1];
    const float* sflow = (const float*)d_in[2];
    const int*   resol = (const int*)d_in[3];
    float* out = (float*)d_out;
    float4* part = (float4*)d_ws;

    const size_t per_chunk = (size_t)BN * sizeof(float4);   // 512 KB
    int SC = 32;
    while (SC > 1 && (size_t)SC * per_chunk > ws_size) SC >>= 1;

    if ((size_t)SC * per_chunk > ws_size) {
        uf2_fused<<<dim3(BN / 1024), dim3(BLOCK), 0, stream>>>(
            xyz, sxyz, sflow, resol, out);
        return;
    }

    dim3 grid(NB * SC), blk(BLOCK);
    switch (SC) {
        case 32: uf2_main<S_ / 32><<<grid, blk, 0, stream>>>(xyz, sxyz, sflow, resol, part); break;
        case 16: uf2_main<S_ / 16><<<grid, blk, 0, stream>>>(xyz, sxyz, sflow, resol, part); break;
        case 8:  uf2_main<S_ / 8 ><<<grid, blk, 0, stream>>>(xyz, sxyz, sflow, resol, part); break;
        case 4:  uf2_main<S_ / 4 ><<<grid, blk, 0, stream>>>(xyz, sxyz, sflow, resol, part); break;
        case 2:  uf2_main<S_ / 2 ><<<grid, blk, 0, stream>>>(xyz, sxyz, sflow, resol, part); break;
        default: uf2_main<S_     ><<<grid, blk, 0, stream>>>(xyz, sxyz, sflow, resol, part); break;
    }
    uf2_combine<<<dim3(BN / BLOCK), dim3(BLOCK), 0, stream>>>(part, out, SC);
}